// Round 1
// baseline (197.790 us; speedup 1.0000x reference)
//
#include <hip/hip_runtime.h>
#include <math.h>

#define CORNER_L 0.05f

__device__ __forceinline__ void euler_R(float yaw, float pitch, float roll, float R[9]) {
    float cy, sy, cp, sp, cr, sr;
    __sincosf(yaw,   &sy, &cy);
    __sincosf(pitch, &sp, &cp);
    __sincosf(roll,  &sr, &cr);
    R[0] = cy * cp;
    R[1] = cy * sp * sr - sy * cr;
    R[2] = cy * sp * cr + sy * sr;
    R[3] = sy * cp;
    R[4] = sy * sp * sr + cy * cr;
    R[5] = sy * sp * cr - cy * sr;
    R[6] = -sp;
    R[7] = cp * sr;
    R[8] = cp * cr;
}

__global__ __launch_bounds__(256) void pose_loss_reduce(
    const float* __restrict__ pred_pose,
    const float* __restrict__ pred_class,
    const float* __restrict__ target_pose,
    const float* __restrict__ target_class,
    float* __restrict__ ws, int B)
{
    const int tid    = blockIdx.x * blockDim.x + threadIdx.x;
    const int stride = gridDim.x * blockDim.x;

    float pose_acc  = 0.0f;   // sum of per-corner norms (will divide by 8*B later)
    float class_acc = 0.0f;   // sum of squared class diffs (divide by 16*B later)

    const float4* __restrict__ pc4 = (const float4*)pred_class;
    const float4* __restrict__ tc4 = (const float4*)target_class;

    for (int i = tid; i < B; i += stride) {
        // ---- class MSE: 16 floats per element, float4 x4 ----
        #pragma unroll
        for (int k = 0; k < 4; ++k) {
            float4 p = pc4[(size_t)i * 4 + k];
            float4 t = tc4[(size_t)i * 4 + k];
            float dx = p.x - t.x, dy = p.y - t.y, dz = p.z - t.z, dw = p.w - t.w;
            class_acc += dx * dx + dy * dy + dz * dz + dw * dw;
        }

        // ---- pose: diff of transformed corners ----
        const float* pp = pred_pose   + (size_t)i * 6;
        const float* tp = target_pose + (size_t)i * 6;
        float Rp[9], Rg[9];
        euler_R(pp[0], pp[1], pp[2], Rp);
        euler_R(tp[0], tp[1], tp[2], Rg);
        float dtx = pp[3] - tp[3];
        float dty = pp[4] - tp[4];
        float dtz = pp[5] - tp[5];

        // L * (Rp - Rg), per row
        float a0 = CORNER_L * (Rp[0] - Rg[0]), a1 = CORNER_L * (Rp[1] - Rg[1]), a2 = CORNER_L * (Rp[2] - Rg[2]);
        float b0 = CORNER_L * (Rp[3] - Rg[3]), b1 = CORNER_L * (Rp[4] - Rg[4]), b2 = CORNER_L * (Rp[5] - Rg[5]);
        float c0 = CORNER_L * (Rp[6] - Rg[6]), c1 = CORNER_L * (Rp[7] - Rg[7]), c2 = CORNER_L * (Rp[8] - Rg[8]);

        float nsum = 0.0f;
        #pragma unroll
        for (int s = 0; s < 8; ++s) {
            float sx = (s & 4) ? 1.0f : -1.0f;
            float sy = (s & 2) ? 1.0f : -1.0f;
            float sz = (s & 1) ? 1.0f : -1.0f;
            float d0 = sx * a0 + sy * a1 + sz * a2 + dtx;
            float d1 = sx * b0 + sy * b1 + sz * b2 + dty;
            float d2 = sx * c0 + sy * c1 + sz * c2 + dtz;
            nsum += sqrtf(d0 * d0 + d1 * d1 + d2 * d2);
        }
        pose_acc += nsum;
    }

    // ---- wave reduce (64 lanes) ----
    #pragma unroll
    for (int off = 32; off > 0; off >>= 1) {
        pose_acc  += __shfl_down(pose_acc,  off);
        class_acc += __shfl_down(class_acc, off);
    }

    __shared__ float s_pose[4], s_class[4];
    const int lane = threadIdx.x & 63;
    const int wave = threadIdx.x >> 6;
    if (lane == 0) { s_pose[wave] = pose_acc; s_class[wave] = class_acc; }
    __syncthreads();
    if (threadIdx.x == 0) {
        float ps = s_pose[0] + s_pose[1] + s_pose[2] + s_pose[3];
        float cs = s_class[0] + s_class[1] + s_class[2] + s_class[3];
        atomicAdd(&ws[0], ps);
        atomicAdd(&ws[1], cs);
    }
}

__global__ void pose_loss_finalize(const float* __restrict__ ws,
                                   float* __restrict__ out,
                                   float inv_pose, float inv_class)
{
    if (threadIdx.x == 0 && blockIdx.x == 0) {
        float lp = ws[0] * inv_pose;
        float lc = ws[1] * inv_class;
        out[0] = lp + lc;   // total_loss
        out[1] = lp;        // loss_pose
        out[2] = lc;        // class_loss
    }
}

extern "C" void kernel_launch(void* const* d_in, const int* in_sizes, int n_in,
                              void* d_out, int out_size, void* d_ws, size_t ws_size,
                              hipStream_t stream) {
    const float* pred_pose    = (const float*)d_in[0];
    const float* pred_class   = (const float*)d_in[1];
    const float* target_pose  = (const float*)d_in[2];
    const float* target_class = (const float*)d_in[3];
    float* out = (float*)d_out;
    float* ws  = (float*)d_ws;

    const int B = in_sizes[0] / 6;

    // zero the two accumulators (d_ws is poisoned to 0xAA before every launch)
    hipMemsetAsync(ws, 0, 2 * sizeof(float), stream);

    const int block = 256;
    const int grid  = 2048;   // 256 CUs x 8 blocks, grid-stride covers B
    pose_loss_reduce<<<grid, block, 0, stream>>>(pred_pose, pred_class,
                                                 target_pose, target_class, ws, B);

    const float inv_pose  = 1.0f / (8.0f  * (float)B);
    const float inv_class = 1.0f / (16.0f * (float)B);
    pose_loss_finalize<<<1, 64, 0, stream>>>(ws, out, inv_pose, inv_class);
}

// Round 2
// 197.554 us; speedup vs baseline: 1.0012x; 1.0012x over previous
//
#include <hip/hip_runtime.h>
#include <math.h>

#define CORNER_L 0.05f

constexpr int THREADS = 256;
constexpr int BLOCKS  = 1024;

__device__ __forceinline__ void euler_R(float yaw, float pitch, float roll, float R[9]) {
    float cy, sy, cp, sp, cr, sr;
    __sincosf(yaw,   &sy, &cy);
    __sincosf(pitch, &sp, &cp);
    __sincosf(roll,  &sr, &cr);
    R[0] = cy * cp;
    R[1] = cy * sp * sr - sy * cr;
    R[2] = cy * sp * cr + sy * sr;
    R[3] = sy * cp;
    R[4] = sy * sp * sr + cy * cr;
    R[5] = sy * sp * cr - cy * sr;
    R[6] = -sp;
    R[7] = cp * sr;
    R[8] = cp * cr;
}

// one pose pair -> sum of 8 corner-distance norms
__device__ __forceinline__ float pose_elem(
    float py, float pp_, float pr, float ptx, float pty, float ptz,
    float ty, float tp_, float tr, float ttx, float tty, float ttz)
{
    float Rp[9], Rg[9];
    euler_R(py, pp_, pr, Rp);
    euler_R(ty, tp_, tr, Rg);
    float dtx = ptx - ttx;
    float dty = pty - tty;
    float dtz = ptz - ttz;

    float a0 = CORNER_L * (Rp[0] - Rg[0]), a1 = CORNER_L * (Rp[1] - Rg[1]), a2 = CORNER_L * (Rp[2] - Rg[2]);
    float b0 = CORNER_L * (Rp[3] - Rg[3]), b1 = CORNER_L * (Rp[4] - Rg[4]), b2 = CORNER_L * (Rp[5] - Rg[5]);
    float c0 = CORNER_L * (Rp[6] - Rg[6]), c1 = CORNER_L * (Rp[7] - Rg[7]), c2 = CORNER_L * (Rp[8] - Rg[8]);

    float nsum = 0.0f;
    #pragma unroll
    for (int s = 0; s < 8; ++s) {
        float sx = (s & 4) ? 1.0f : -1.0f;
        float sy = (s & 2) ? 1.0f : -1.0f;
        float sz = (s & 1) ? 1.0f : -1.0f;
        float d0 = sx * a0 + sy * a1 + sz * a2 + dtx;
        float d1 = sx * b0 + sy * b1 + sz * b2 + dty;
        float d2 = sx * c0 + sy * c1 + sz * c2 + dtz;
        nsum += sqrtf(d0 * d0 + d1 * d1 + d2 * d2);
    }
    return nsum;
}

// Each block owns a contiguous chunk of B/gridDim elements.
// Class MSE: unit-stride float4 grid-stride within chunk.
// Pose: staged to LDS via unit-stride float4, consumed per-element from LDS.
__global__ __launch_bounds__(THREADS, 4) void pose_loss_reduce(
    const float4* __restrict__ pp4,
    const float4* __restrict__ pc4,
    const float4* __restrict__ tp4,
    const float4* __restrict__ tc4,
    float* __restrict__ ws, int B)
{
    __shared__ float s_p[3072];   // 512 elems * 6 floats
    __shared__ float s_t[3072];

    const int tid = threadIdx.x;
    const int elems_per_blk = B / gridDim.x;         // 1024
    const int elem_base = blockIdx.x * elems_per_blk;

    float class_acc0 = 0.0f, class_acc1 = 0.0f;
    float pose_acc = 0.0f;

    // ---- class MSE: chunk is elems_per_blk*4 float4s per array, unit-stride ----
    {
        const int n4 = elems_per_blk * 4;            // 4096
        const size_t base = (size_t)elem_base * 4;
        #pragma unroll 4
        for (int k = tid; k < n4; k += 2 * THREADS) {
            float4 p0 = pc4[base + k];
            float4 t0 = tc4[base + k];
            float4 p1 = pc4[base + k + THREADS];
            float4 t1 = tc4[base + k + THREADS];
            float dx0 = p0.x - t0.x, dy0 = p0.y - t0.y, dz0 = p0.z - t0.z, dw0 = p0.w - t0.w;
            float dx1 = p1.x - t1.x, dy1 = p1.y - t1.y, dz1 = p1.z - t1.z, dw1 = p1.w - t1.w;
            class_acc0 += dx0 * dx0 + dy0 * dy0 + dz0 * dz0 + dw0 * dw0;
            class_acc1 += dx1 * dx1 + dy1 * dy1 + dz1 * dz1 + dw1 * dw1;
        }
    }
    float class_acc = class_acc0 + class_acc1;

    // ---- pose: two subchunks of 512 elements, LDS-staged ----
    const int sub_elems = elems_per_blk / 2;         // 512
    float4* sp4 = (float4*)s_p;
    float4* st4 = (float4*)s_t;
    for (int sc = 0; sc < 2; ++sc) {
        const int ebase = elem_base + sc * sub_elems;
        const int nf4 = sub_elems * 6 / 4;           // 768 float4 per array
        const size_t gbase = (size_t)ebase * 6 / 4;  // ebase multiple of 512 -> exact
        #pragma unroll
        for (int k = tid; k < 768; k += THREADS) {   // 3 iters
            sp4[k] = pp4[gbase + k];
            st4[k] = tp4[gbase + k];
        }
        __syncthreads();
        // 2 elements per thread: 12 consecutive floats = 3 float4
        {
            float4 A  = sp4[tid * 3 + 0];
            float4 Bv = sp4[tid * 3 + 1];
            float4 Cv = sp4[tid * 3 + 2];
            float4 D  = st4[tid * 3 + 0];
            float4 E  = st4[tid * 3 + 1];
            float4 F  = st4[tid * 3 + 2];
            pose_acc += pose_elem(A.x, A.y, A.z, A.w, Bv.x, Bv.y,
                                  D.x, D.y, D.z, D.w, E.x, E.y);
            pose_acc += pose_elem(Bv.z, Bv.w, Cv.x, Cv.y, Cv.z, Cv.w,
                                  E.z, E.w, F.x, F.y, F.z, F.w);
        }
        __syncthreads();
    }

    // ---- block reduction ----
    #pragma unroll
    for (int off = 32; off > 0; off >>= 1) {
        pose_acc  += __shfl_down(pose_acc,  off);
        class_acc += __shfl_down(class_acc, off);
    }
    __shared__ float r_pose[4], r_class[4];
    const int lane = tid & 63;
    const int wave = tid >> 6;
    if (lane == 0) { r_pose[wave] = pose_acc; r_class[wave] = class_acc; }
    __syncthreads();
    if (tid == 0) {
        ws[blockIdx.x]             = r_pose[0] + r_pose[1] + r_pose[2] + r_pose[3];
        ws[gridDim.x + blockIdx.x] = r_class[0] + r_class[1] + r_class[2] + r_class[3];
    }
}

__global__ __launch_bounds__(THREADS) void pose_loss_finalize(
    const float* __restrict__ ws, float* __restrict__ out,
    int nblocks, float inv_pose, float inv_class)
{
    float p = 0.0f, c = 0.0f;
    for (int k = threadIdx.x; k < nblocks; k += THREADS) {
        p += ws[k];
        c += ws[nblocks + k];
    }
    #pragma unroll
    for (int off = 32; off > 0; off >>= 1) {
        p += __shfl_down(p, off);
        c += __shfl_down(c, off);
    }
    __shared__ float r_p[4], r_c[4];
    const int lane = threadIdx.x & 63;
    const int wave = threadIdx.x >> 6;
    if (lane == 0) { r_p[wave] = p; r_c[wave] = c; }
    __syncthreads();
    if (threadIdx.x == 0) {
        float lp = (r_p[0] + r_p[1] + r_p[2] + r_p[3]) * inv_pose;
        float lc = (r_c[0] + r_c[1] + r_c[2] + r_c[3]) * inv_class;
        out[0] = lp + lc;
        out[1] = lp;
        out[2] = lc;
    }
}

extern "C" void kernel_launch(void* const* d_in, const int* in_sizes, int n_in,
                              void* d_out, int out_size, void* d_ws, size_t ws_size,
                              hipStream_t stream) {
    const float4* pred_pose    = (const float4*)d_in[0];
    const float4* pred_class   = (const float4*)d_in[1];
    const float4* target_pose  = (const float4*)d_in[2];
    const float4* target_class = (const float4*)d_in[3];
    float* out = (float*)d_out;
    float* ws  = (float*)d_ws;

    const int B = in_sizes[0] / 6;

    pose_loss_reduce<<<BLOCKS, THREADS, 0, stream>>>(pred_pose, pred_class,
                                                     target_pose, target_class, ws, B);

    const float inv_pose  = 1.0f / (8.0f  * (float)B);
    const float inv_class = 1.0f / (16.0f * (float)B);
    pose_loss_finalize<<<1, THREADS, 0, stream>>>(ws, out, BLOCKS, inv_pose, inv_class);
}

// Round 3
// 191.495 us; speedup vs baseline: 1.0329x; 1.0316x over previous
//
#include <hip/hip_runtime.h>
#include <math.h>

#define CORNER_L 0.05f

constexpr int THREADS      = 256;
constexpr int CLASS_BLOCKS = 1024;   // streaming MSE blocks
constexpr int POSE_BLOCKS  = 512;    // trig/compute blocks
constexpr int TOTAL_BLOCKS = CLASS_BLOCKS + POSE_BLOCKS;   // 1536

__device__ __forceinline__ void euler_R(float yaw, float pitch, float roll, float R[9]) {
    float cy, sy, cp, sp, cr, sr;
    __sincosf(yaw,   &sy, &cy);
    __sincosf(pitch, &sp, &cp);
    __sincosf(roll,  &sr, &cr);
    R[0] = cy * cp;
    R[1] = cy * sp * sr - sy * cr;
    R[2] = cy * sp * cr + sy * sr;
    R[3] = sy * cp;
    R[4] = sy * sp * sr + cy * cr;
    R[5] = sy * sp * cr - cy * sr;
    R[6] = -sp;
    R[7] = cp * sr;
    R[8] = cp * cr;
}

__device__ __forceinline__ float pose_elem(
    float py, float pp_, float pr, float ptx, float pty, float ptz,
    float ty, float tp_, float tr, float ttx, float tty, float ttz)
{
    float Rp[9], Rg[9];
    euler_R(py, pp_, pr, Rp);
    euler_R(ty, tp_, tr, Rg);
    float dtx = ptx - ttx;
    float dty = pty - tty;
    float dtz = ptz - ttz;

    float a0 = CORNER_L * (Rp[0] - Rg[0]), a1 = CORNER_L * (Rp[1] - Rg[1]), a2 = CORNER_L * (Rp[2] - Rg[2]);
    float b0 = CORNER_L * (Rp[3] - Rg[3]), b1 = CORNER_L * (Rp[4] - Rg[4]), b2 = CORNER_L * (Rp[5] - Rg[5]);
    float c0 = CORNER_L * (Rp[6] - Rg[6]), c1 = CORNER_L * (Rp[7] - Rg[7]), c2 = CORNER_L * (Rp[8] - Rg[8]);

    float nsum = 0.0f;
    #pragma unroll
    for (int s = 0; s < 8; ++s) {
        float sx = (s & 4) ? 1.0f : -1.0f;
        float sy = (s & 2) ? 1.0f : -1.0f;
        float sz = (s & 1) ? 1.0f : -1.0f;
        float d0 = sx * a0 + sy * a1 + sz * a2 + dtx;
        float d1 = sx * b0 + sy * b1 + sz * b2 + dty;
        float d2 = sx * c0 + sy * c1 + sz * c2 + dtz;
        nsum += sqrtf(d0 * d0 + d1 * d1 + d2 * d2);
    }
    return nsum;
}

// Block-partitioned kernel: blockIdx%3 in {0,1} -> class-MSE streaming,
// blockIdx%3 == 2 -> pose. Interleaved so both types are co-resident.
__global__ __launch_bounds__(THREADS, 4) void pose_loss_reduce(
    const float4* __restrict__ pp4,
    const float4* __restrict__ pc4,
    const float4* __restrict__ tp4,
    const float4* __restrict__ tc4,
    float* __restrict__ ws, int B)
{
    const int tid = threadIdx.x;
    const int g   = blockIdx.x;
    const int q   = g / 3;
    const int r   = g - q * 3;

    float pose_acc  = 0.0f;
    float class_acc = 0.0f;

    if (r < 2) {
        // ================= class MSE streaming =================
        const int cb = q * 2 + r;                       // 0..1023
        const size_t cbase = (size_t)cb * 4096;         // 4096 float4 per array per block
        float acc0 = 0.f, acc1 = 0.f;
        #pragma unroll
        for (int round = 0; round < 2; ++round) {
            const size_t base = cbase + round * 2048 + tid;
            float4 p[8], t[8];
            #pragma unroll
            for (int j = 0; j < 8; ++j) p[j] = pc4[base + j * 256];
            #pragma unroll
            for (int j = 0; j < 8; ++j) t[j] = tc4[base + j * 256];
            #pragma unroll
            for (int j = 0; j < 8; ++j) {
                float dx = p[j].x - t[j].x, dy = p[j].y - t[j].y;
                float dz = p[j].z - t[j].z, dw = p[j].w - t[j].w;
                if (j & 1) acc1 += dx * dx + dy * dy + dz * dz + dw * dw;
                else       acc0 += dx * dx + dy * dy + dz * dz + dw * dw;
            }
        }
        class_acc = acc0 + acc1;
    } else {
        // ================= pose =================
        const int pb = q;                               // 0..511
        const size_t ebase = (size_t)pb * 2048;         // 2048 elements per block
        #pragma unroll
        for (int round = 0; round < 2; ++round) {
            const size_t elem0 = ebase + round * 1024 + tid * 4;   // 4 elements
            const size_t f4 = (elem0 >> 2) * 6;                    // 6 float4 per 4 elems
            float4 P[6], T[6];
            #pragma unroll
            for (int j = 0; j < 6; ++j) P[j] = pp4[f4 + j];
            #pragma unroll
            for (int j = 0; j < 6; ++j) T[j] = tp4[f4 + j];

            pose_acc += pose_elem(P[0].x, P[0].y, P[0].z, P[0].w, P[1].x, P[1].y,
                                  T[0].x, T[0].y, T[0].z, T[0].w, T[1].x, T[1].y);
            pose_acc += pose_elem(P[1].z, P[1].w, P[2].x, P[2].y, P[2].z, P[2].w,
                                  T[1].z, T[1].w, T[2].x, T[2].y, T[2].z, T[2].w);
            pose_acc += pose_elem(P[3].x, P[3].y, P[3].z, P[3].w, P[4].x, P[4].y,
                                  T[3].x, T[3].y, T[3].z, T[3].w, T[4].x, T[4].y);
            pose_acc += pose_elem(P[4].z, P[4].w, P[5].x, P[5].y, P[5].z, P[5].w,
                                  T[4].z, T[4].w, T[5].x, T[5].y, T[5].z, T[5].w);
        }
    }

    // ---- block reduction (both partials; one of them is zero per block) ----
    #pragma unroll
    for (int off = 32; off > 0; off >>= 1) {
        pose_acc  += __shfl_down(pose_acc,  off);
        class_acc += __shfl_down(class_acc, off);
    }
    __shared__ float r_pose[4], r_class[4];
    const int lane = tid & 63;
    const int wave = tid >> 6;
    if (lane == 0) { r_pose[wave] = pose_acc; r_class[wave] = class_acc; }
    __syncthreads();
    if (tid == 0) {
        ws[2 * g]     = r_pose[0] + r_pose[1] + r_pose[2] + r_pose[3];
        ws[2 * g + 1] = r_class[0] + r_class[1] + r_class[2] + r_class[3];
    }
}

__global__ __launch_bounds__(THREADS) void pose_loss_finalize(
    const float* __restrict__ ws, float* __restrict__ out,
    int nblocks, float inv_pose, float inv_class)
{
    float p = 0.0f, c = 0.0f;
    for (int k = threadIdx.x; k < nblocks; k += THREADS) {
        p += ws[2 * k];
        c += ws[2 * k + 1];
    }
    #pragma unroll
    for (int off = 32; off > 0; off >>= 1) {
        p += __shfl_down(p, off);
        c += __shfl_down(c, off);
    }
    __shared__ float r_p[4], r_c[4];
    const int lane = threadIdx.x & 63;
    const int wave = threadIdx.x >> 6;
    if (lane == 0) { r_p[wave] = p; r_c[wave] = c; }
    __syncthreads();
    if (threadIdx.x == 0) {
        float lp = (r_p[0] + r_p[1] + r_p[2] + r_p[3]) * inv_pose;
        float lc = (r_c[0] + r_c[1] + r_c[2] + r_c[3]) * inv_class;
        out[0] = lp + lc;
        out[1] = lp;
        out[2] = lc;
    }
}

extern "C" void kernel_launch(void* const* d_in, const int* in_sizes, int n_in,
                              void* d_out, int out_size, void* d_ws, size_t ws_size,
                              hipStream_t stream) {
    const float4* pred_pose    = (const float4*)d_in[0];
    const float4* pred_class   = (const float4*)d_in[1];
    const float4* target_pose  = (const float4*)d_in[2];
    const float4* target_class = (const float4*)d_in[3];
    float* out = (float*)d_out;
    float* ws  = (float*)d_ws;

    const int B = in_sizes[0] / 6;

    pose_loss_reduce<<<TOTAL_BLOCKS, THREADS, 0, stream>>>(pred_pose, pred_class,
                                                           target_pose, target_class, ws, B);

    const float inv_pose  = 1.0f / (8.0f  * (float)B);
    const float inv_class = 1.0f / (16.0f * (float)B);
    pose_loss_finalize<<<1, THREADS, 0, stream>>>(ws, out, TOTAL_BLOCKS, inv_pose, inv_class);
}

// Round 4
// 189.039 us; speedup vs baseline: 1.0463x; 1.0130x over previous
//
#include <hip/hip_runtime.h>
#include <math.h>

#define CORNER_L 0.05f

constexpr int THREADS = 256;
constexpr int BLOCKS  = 2048;                 // 524288 threads
// B = 1048576 elements. Class: 4*B float4 per array -> 8 per thread.
// Pose: each thread handles 2 elements = 3 float4 per array.

// Fully scalar, pointer-free: 12 native sin/cos, 9 R-entry diffs, 8 corner norms.
__device__ __forceinline__ float pose_elem(
    float py, float pp_, float pr, float ptx, float pty, float ptz,
    float ty, float tp_, float tr, float ttx, float tty, float ttz)
{
    float sy1 = __sinf(py),  cy1 = __cosf(py);
    float sp1 = __sinf(pp_), cp1 = __cosf(pp_);
    float sr1 = __sinf(pr),  cr1 = __cosf(pr);
    float sy2 = __sinf(ty),  cy2 = __cosf(ty);
    float sp2 = __sinf(tp_), cp2 = __cosf(tp_);
    float sr2 = __sinf(tr),  cr2 = __cosf(tr);

    float a0 = CORNER_L * (cy1 * cp1 - cy2 * cp2);
    float a1 = CORNER_L * ((cy1 * sp1 * sr1 - sy1 * cr1) - (cy2 * sp2 * sr2 - sy2 * cr2));
    float a2 = CORNER_L * ((cy1 * sp1 * cr1 + sy1 * sr1) - (cy2 * sp2 * cr2 + sy2 * sr2));
    float b0 = CORNER_L * (sy1 * cp1 - sy2 * cp2);
    float b1 = CORNER_L * ((sy1 * sp1 * sr1 + cy1 * cr1) - (sy2 * sp2 * sr2 + cy2 * cr2));
    float b2 = CORNER_L * ((sy1 * sp1 * cr1 - cy1 * sr1) - (sy2 * sp2 * cr2 - cy2 * sr2));
    float c0 = CORNER_L * (sp2 - sp1);
    float c1 = CORNER_L * (cp1 * sr1 - cp2 * sr2);
    float c2 = CORNER_L * (cp1 * cr1 - cp2 * cr2);
    float dtx = ptx - ttx;
    float dty = pty - tty;
    float dtz = ptz - ttz;

    float nsum = 0.0f;
    #pragma unroll
    for (int s = 0; s < 8; ++s) {
        float sx = (s & 4) ? 1.0f : -1.0f;
        float sy = (s & 2) ? 1.0f : -1.0f;
        float sz = (s & 1) ? 1.0f : -1.0f;
        float d0 = sx * a0 + sy * a1 + sz * a2 + dtx;
        float d1 = sx * b0 + sy * b1 + sz * b2 + dty;
        float d2 = sx * c0 + sy * c1 + sz * c2 + dtz;
        nsum += __builtin_amdgcn_sqrtf(d0 * d0 + d1 * d1 + d2 * d2);
    }
    return nsum;
}

__global__ __launch_bounds__(THREADS, 4) void pose_loss_reduce(
    const float4* __restrict__ pp4,
    const float4* __restrict__ pc4,
    const float4* __restrict__ tp4,
    const float4* __restrict__ tc4,
    float* __restrict__ ws, int B)
{
    const int tid  = threadIdx.x;
    const size_t gtid = (size_t)blockIdx.x * THREADS + tid;
    const size_t G    = (size_t)BLOCKS * THREADS;        // 524288

    // ---- class MSE: 8 float4 per thread per array, batched 4 for ILP ----
    float class_acc = 0.0f;
    {
        float acc0 = 0.f, acc1 = 0.f, acc2 = 0.f, acc3 = 0.f;
        #pragma unroll
        for (int r = 0; r < 2; ++r) {
            const size_t base = gtid + (size_t)r * 4 * G;
            float4 p0 = pc4[base];
            float4 p1 = pc4[base + G];
            float4 p2 = pc4[base + 2 * G];
            float4 p3 = pc4[base + 3 * G];
            float4 t0 = tc4[base];
            float4 t1 = tc4[base + G];
            float4 t2 = tc4[base + 2 * G];
            float4 t3 = tc4[base + 3 * G];
            float dx, dy, dz, dw;
            dx = p0.x - t0.x; dy = p0.y - t0.y; dz = p0.z - t0.z; dw = p0.w - t0.w;
            acc0 += dx * dx + dy * dy + dz * dz + dw * dw;
            dx = p1.x - t1.x; dy = p1.y - t1.y; dz = p1.z - t1.z; dw = p1.w - t1.w;
            acc1 += dx * dx + dy * dy + dz * dz + dw * dw;
            dx = p2.x - t2.x; dy = p2.y - t2.y; dz = p2.z - t2.z; dw = p2.w - t2.w;
            acc2 += dx * dx + dy * dy + dz * dz + dw * dw;
            dx = p3.x - t3.x; dy = p3.y - t3.y; dz = p3.z - t3.z; dw = p3.w - t3.w;
            acc3 += dx * dx + dy * dy + dz * dz + dw * dw;
        }
        class_acc = (acc0 + acc1) + (acc2 + acc3);
    }

    // ---- pose: 2 consecutive elements per thread = 3 float4 per array ----
    float pose_acc = 0.0f;
    {
        const size_t f4 = gtid * 3;
        float4 P0 = pp4[f4], P1 = pp4[f4 + 1], P2 = pp4[f4 + 2];
        float4 T0 = tp4[f4], T1 = tp4[f4 + 1], T2 = tp4[f4 + 2];
        pose_acc += pose_elem(P0.x, P0.y, P0.z, P0.w, P1.x, P1.y,
                              T0.x, T0.y, T0.z, T0.w, T1.x, T1.y);
        pose_acc += pose_elem(P1.z, P1.w, P2.x, P2.y, P2.z, P2.w,
                              T1.z, T1.w, T2.x, T2.y, T2.z, T2.w);
    }

    // ---- block reduction ----
    #pragma unroll
    for (int off = 32; off > 0; off >>= 1) {
        pose_acc  += __shfl_down(pose_acc,  off);
        class_acc += __shfl_down(class_acc, off);
    }
    __shared__ float r_pose[4], r_class[4];
    const int lane = tid & 63;
    const int wave = tid >> 6;
    if (lane == 0) { r_pose[wave] = pose_acc; r_class[wave] = class_acc; }
    __syncthreads();
    if (tid == 0) {
        ws[2 * blockIdx.x]     = r_pose[0] + r_pose[1] + r_pose[2] + r_pose[3];
        ws[2 * blockIdx.x + 1] = r_class[0] + r_class[1] + r_class[2] + r_class[3];
    }
}

__global__ __launch_bounds__(THREADS) void pose_loss_finalize(
    const float* __restrict__ ws, float* __restrict__ out,
    int nblocks, float inv_pose, float inv_class)
{
    float p = 0.0f, c = 0.0f;
    for (int k = threadIdx.x; k < nblocks; k += THREADS) {
        p += ws[2 * k];
        c += ws[2 * k + 1];
    }
    #pragma unroll
    for (int off = 32; off > 0; off >>= 1) {
        p += __shfl_down(p, off);
        c += __shfl_down(c, off);
    }
    __shared__ float r_p[4], r_c[4];
    const int lane = threadIdx.x & 63;
    const int wave = threadIdx.x >> 6;
    if (lane == 0) { r_p[wave] = p; r_c[wave] = c; }
    __syncthreads();
    if (threadIdx.x == 0) {
        float lp = (r_p[0] + r_p[1] + r_p[2] + r_p[3]) * inv_pose;
        float lc = (r_c[0] + r_c[1] + r_c[2] + r_c[3]) * inv_class;
        out[0] = lp + lc;
        out[1] = lp;
        out[2] = lc;
    }
}

extern "C" void kernel_launch(void* const* d_in, const int* in_sizes, int n_in,
                              void* d_out, int out_size, void* d_ws, size_t ws_size,
                              hipStream_t stream) {
    const float4* pred_pose    = (const float4*)d_in[0];
    const float4* pred_class   = (const float4*)d_in[1];
    const float4* target_pose  = (const float4*)d_in[2];
    const float4* target_class = (const float4*)d_in[3];
    float* out = (float*)d_out;
    float* ws  = (float*)d_ws;

    const int B = in_sizes[0] / 6;

    pose_loss_reduce<<<BLOCKS, THREADS, 0, stream>>>(pred_pose, pred_class,
                                                     target_pose, target_class, ws, B);

    const float inv_pose  = 1.0f / (8.0f  * (float)B);
    const float inv_class = 1.0f / (16.0f * (float)B);
    pose_loss_finalize<<<1, THREADS, 0, stream>>>(ws, out, BLOCKS, inv_pose, inv_class);
}